// Round 1
// baseline (9812.808 us; speedup 1.0000x reference)
//
#include <hip/hip_runtime.h>

#define N_NODES 50000
#define N_EDGES 800000
#define PDIM 3
#define FDIM 64
#define MDIM 32
#define NLAYERS 2
#define EINDIM 129      // 2F+1
#define H1 258          // 2*EIN
#define CH 128          // 4*M
#define NH 128          // 2*F
#define XDIM 67         // P+F
#define W1P_STRIDE 260  // padded 258 -> 260 for float4 alignment

__device__ __forceinline__ float fsilu(float x) {
  return x / (1.0f + __expf(-x));
}

// pad eW1 [L][129][258] -> [L][129][260]
__global__ void prep_w1(const float* __restrict__ eW1, float* __restrict__ w1p) {
  int idx = blockIdx.x * blockDim.x + threadIdx.x;
  const int total = NLAYERS * EINDIM * H1;
  if (idx >= total) return;
  int j = idx % H1;
  int rest = idx / H1;
  int k = rest % EINDIM;
  int l = rest / EINDIM;
  w1p[(l * EINDIM + k) * W1P_STRIDE + j] = eW1[idx];
}

__global__ __launch_bounds__(256, 2)
void edge_kernel(const float* __restrict__ X,
                 const int* __restrict__ ei,
                 const float* __restrict__ w1p, const float* __restrict__ eb1,
                 const float* __restrict__ eW2, const float* __restrict__ eb2,
                 const float* __restrict__ cW1, const float* __restrict__ cb1,
                 const float* __restrict__ cW2, const float* __restrict__ cb2,
                 const float* __restrict__ cscale,
                 float* __restrict__ m_acc, float* __restrict__ mh_acc,
                 int layer)
{
  __shared__ float ein[32 * EINDIM];   // stride 129 (==1 mod 32: conflict-free)
  __shared__ float hs[32 * H1];        // stride 258 (2-way: free)
  __shared__ float ml[32 * 33];        // stride 33: conflict-free
  __shared__ float rel3[32 * 3];
  __shared__ float cpart[8 * 32];
  __shared__ int sd[2][32];

  const int tid = threadIdx.x;
  const int e_loc = tid & 31;
  const int jg = tid >> 5;           // 0..7
  const int e0 = blockIdx.x * 32;

  if (tid < 32) {
    sd[0][tid] = ei[e0 + tid];            // src
    sd[1][tid] = ei[N_EDGES + e0 + tid];  // dst
  }
  __syncthreads();

  // stage e_in = [feats[dst](64), feats[src](64), rel_dist]
  for (int idx = tid; idx < 32 * 128; idx += 256) {
    int e = idx >> 7;
    int k = idx & 127;
    int node = (k < 64) ? sd[1][e] : sd[0][e];
    ein[e * EINDIM + k] = X[node * XDIM + PDIM + (k & 63)];
  }
  if (tid < 32) {
    int s = sd[0][tid], d = sd[1][tid];
    float rx = X[s * XDIM + 0] - X[d * XDIM + 0];
    float ry = X[s * XDIM + 1] - X[d * XDIM + 1];
    float rz = X[s * XDIM + 2] - X[d * XDIM + 2];
    rel3[tid * 3 + 0] = rx;
    rel3[tid * 3 + 1] = ry;
    rel3[tid * 3 + 2] = rz;
    ein[tid * EINDIM + 128] = rx * rx + ry * ry + rz * rz;
  }
  __syncthreads();

  // ---- phase 1: h = silu(e_in @ W1 + b1), [32][258] ----
  const float* W1 = w1p + layer * EINDIM * W1P_STRIDE;
  const float* B1 = eb1 + layer * H1;
  for (int pass = 0; pass < 4; ++pass) {
    const int j0 = jg * 32 + pass * 8;
    float acc[8];
    #pragma unroll
    for (int i = 0; i < 8; ++i) acc[i] = B1[j0 + i];
    #pragma unroll 2
    for (int k = 0; k < EINDIM; ++k) {
      float a = ein[e_loc * EINDIM + k];
      const float4 w0 = *reinterpret_cast<const float4*>(W1 + k * W1P_STRIDE + j0);
      const float4 w1 = *reinterpret_cast<const float4*>(W1 + k * W1P_STRIDE + j0 + 4);
      acc[0] = fmaf(a, w0.x, acc[0]);
      acc[1] = fmaf(a, w0.y, acc[1]);
      acc[2] = fmaf(a, w0.z, acc[2]);
      acc[3] = fmaf(a, w0.w, acc[3]);
      acc[4] = fmaf(a, w1.x, acc[4]);
      acc[5] = fmaf(a, w1.y, acc[5]);
      acc[6] = fmaf(a, w1.z, acc[6]);
      acc[7] = fmaf(a, w1.w, acc[7]);
    }
    #pragma unroll
    for (int i = 0; i < 8; ++i) hs[e_loc * H1 + j0 + i] = fsilu(acc[i]);
  }
  if (jg < 2) {  // tail j = 256, 257
    const int j = 256 + jg;
    float acc = B1[j];
    for (int k = 0; k < EINDIM; ++k)
      acc = fmaf(ein[e_loc * EINDIM + k], W1[k * W1P_STRIDE + j], acc);
    hs[e_loc * H1 + j] = fsilu(acc);
  }
  __syncthreads();

  // ---- phase 2: m_ij = silu(h @ W2 + b2), [32][32] ----
  const float* W2 = eW2 + layer * H1 * MDIM;
  const float* B2 = eb2 + layer * MDIM;
  const int j4 = jg * 4;
  float macc[4];
  #pragma unroll
  for (int i = 0; i < 4; ++i) macc[i] = B2[j4 + i];
  #pragma unroll 2
  for (int k = 0; k < H1; ++k) {
    float hv = hs[e_loc * H1 + k];
    const float4 w = *reinterpret_cast<const float4*>(W2 + k * MDIM + j4);
    macc[0] = fmaf(hv, w.x, macc[0]);
    macc[1] = fmaf(hv, w.y, macc[1]);
    macc[2] = fmaf(hv, w.z, macc[2]);
    macc[3] = fmaf(hv, w.w, macc[3]);
  }
  const int dnode = sd[1][e_loc];
  #pragma unroll
  for (int i = 0; i < 4; ++i) {
    float mval = fsilu(macc[i]);
    ml[e_loc * 33 + j4 + i] = mval;
    atomicAdd(&m_acc[dnode * MDIM + j4 + i], mval);
  }
  __syncthreads();

  // ---- phase 3: cw = tanh(silu(m @ cW1 + cb1) @ cW2 + cb2) ----
  const float* CW1 = cW1 + layer * MDIM * CH;
  const float* CB1 = cb1 + layer * CH;
  const float* CW2 = cW2 + layer * CH;
  const int j16 = jg * 16;
  float cacc[16];
  #pragma unroll
  for (int i = 0; i < 16; ++i) cacc[i] = CB1[j16 + i];
  for (int k = 0; k < MDIM; ++k) {
    float mvv = ml[e_loc * 33 + k];
    #pragma unroll
    for (int i = 0; i < 16; i += 4) {
      const float4 w = *reinterpret_cast<const float4*>(CW1 + k * CH + j16 + i);
      cacc[i + 0] = fmaf(mvv, w.x, cacc[i + 0]);
      cacc[i + 1] = fmaf(mvv, w.y, cacc[i + 1]);
      cacc[i + 2] = fmaf(mvv, w.z, cacc[i + 2]);
      cacc[i + 3] = fmaf(mvv, w.w, cacc[i + 3]);
    }
  }
  float part = 0.0f;
  #pragma unroll
  for (int i = 0; i < 16; ++i) part += fsilu(cacc[i]) * CW2[j16 + i];
  cpart[jg * 32 + e_loc] = part;
  __syncthreads();

  if (tid < 32) {
    float s = cb2[layer];
    #pragma unroll
    for (int g = 0; g < 8; ++g) s += cpart[g * 32 + tid];
    float cw = tanhf(s);
    float dist = ein[tid * EINDIM + 128];
    float nrm = sqrtf(dist);
    float fac = cw * cscale[layer] / fmaxf(nrm, 1e-8f);
    int d = sd[1][tid];
    atomicAdd(&mh_acc[d * 3 + 0], fac * rel3[tid * 3 + 0]);
    atomicAdd(&mh_acc[d * 3 + 1], fac * rel3[tid * 3 + 1]);
    atomicAdd(&mh_acc[d * 3 + 2], fac * rel3[tid * 3 + 2]);
  }
}

__global__ __launch_bounds__(256)
void node_kernel(const float* __restrict__ Xin,
                 const float* __restrict__ m_acc, const float* __restrict__ mh_acc,
                 const float* __restrict__ nW1, const float* __restrict__ nb1,
                 const float* __restrict__ nW2, const float* __restrict__ nb2,
                 float* __restrict__ Xout, int layer)
{
  __shared__ float nin[4][97];
  __shared__ float hn[4][NH + 1];
  const int tid = threadIdx.x;
  const int w = tid >> 6;
  const int lane = tid & 63;
  const int n = blockIdx.x * 4 + w;

  nin[w][lane] = Xin[n * XDIM + PDIM + lane];
  if (lane < MDIM) nin[w][FDIM + lane] = m_acc[n * MDIM + lane];
  __syncthreads();

  const float* W1 = nW1 + layer * (FDIM + MDIM) * NH;
  const float* B1 = nb1 + layer * NH;
  float a0 = B1[lane];
  float a1 = B1[lane + 64];
  #pragma unroll 4
  for (int k = 0; k < FDIM + MDIM; ++k) {
    float v = nin[w][k];
    a0 = fmaf(v, W1[k * NH + lane], a0);
    a1 = fmaf(v, W1[k * NH + lane + 64], a1);
  }
  hn[w][lane] = fsilu(a0);
  hn[w][lane + 64] = fsilu(a1);
  __syncthreads();

  const float* W2 = nW2 + layer * NH * FDIM;
  float acc = nb2[layer * FDIM + lane];
  #pragma unroll 4
  for (int k = 0; k < NH; ++k)
    acc = fmaf(hn[w][k], W2[k * FDIM + lane], acc);

  float feat = Xin[n * XDIM + PDIM + lane];
  Xout[n * XDIM + PDIM + lane] = feat + acc;
  if (lane < PDIM)
    Xout[n * XDIM + lane] = Xin[n * XDIM + lane] + mh_acc[n * PDIM + lane];
}

extern "C" void kernel_launch(void* const* d_in, const int* in_sizes, int n_in,
                              void* d_out, int out_size, void* d_ws, size_t ws_size,
                              hipStream_t stream) {
  const float* x      = (const float*)d_in[0];
  const int*   ei     = (const int*)d_in[1];
  const float* eW1    = (const float*)d_in[2];
  const float* eb1    = (const float*)d_in[3];
  const float* eW2    = (const float*)d_in[4];
  const float* eb2    = (const float*)d_in[5];
  const float* cW1    = (const float*)d_in[6];
  const float* cb1    = (const float*)d_in[7];
  const float* cW2    = (const float*)d_in[8];
  const float* cb2    = (const float*)d_in[9];
  const float* nW1    = (const float*)d_in[10];
  const float* nb1    = (const float*)d_in[11];
  const float* nW2    = (const float*)d_in[12];
  const float* nb2    = (const float*)d_in[13];
  const float* cscale = (const float*)d_in[14];

  float* ws    = (float*)d_ws;
  float* X1    = ws;                        // N*67
  float* m_acc = X1 + N_NODES * XDIM;       // N*32
  float* mh_acc = m_acc + N_NODES * MDIM;   // N*3
  float* w1p   = mh_acc + N_NODES * PDIM;   // 2*129*260

  prep_w1<<<(NLAYERS * EINDIM * H1 + 255) / 256, 256, 0, stream>>>(eW1, w1p);

  for (int l = 0; l < NLAYERS; ++l) {
    hipMemsetAsync(m_acc, 0, (size_t)(N_NODES * MDIM + N_NODES * PDIM) * sizeof(float), stream);
    const float* Xin = (l == 0) ? x : X1;
    float* Xout = (l == 0) ? X1 : (float*)d_out;
    edge_kernel<<<N_EDGES / 32, 256, 0, stream>>>(
        Xin, ei, w1p, eb1, eW2, eb2, cW1, cb1, cW2, cb2, cscale, m_acc, mh_acc, l);
    node_kernel<<<N_NODES / 4, 256, 0, stream>>>(
        Xin, m_acc, mh_acc, nW1, nb1, nW2, nb2, Xout, l);
  }
}